// Round 6
// baseline (454.377 us; speedup 1.0000x reference)
//
#include <hip/hip_runtime.h>

// HyperConnections fused kernel, v6r (resubmit of v6 — round-5 bench died in
// container acquisition, not in the kernel: source is compile-clean, has no
// barriers/workspace/exotic builtins, and a finite grid-stride loop).
//
// out[(b*S+s)*T+t, d] = res[...] + c[s] * rmsnorm(sum_s h_pre[s]*res[...])[d]
// where c[s] = sum_r Sinkhorn(exp(H_res))[s][r] * 2*sigmoid(H_post[r]).
//
// v6 changes vs v5 (451.5 us, main ~119 us @ ~4.5 TB/s):
//  - Wave-autonomous: one WAVE owns one t-row (64 lanes x 16 floats = D).
//    Sum-of-squares = per-lane 16-elem sum + 6-step shfl_xor butterfly.
//    NO LDS, NO __syncthreads -> no vmcnt(0) drain between loads and
//    stores (the barrier forced a full load drain per 64 KiB in v5).
//  - Persistent grid-stride loop, 1024 blocks (Guideline 11): weight
//    hoisted and loaded once per wave; 4 rows per wave; loads of the next
//    row can overlap stores of the current one (nothing orders them).
//  - Coefficients stay hoisted in the 1-block precompute kernel.

#define S_ 4
#define T_ 4096
#define D_ 1024
#define NITER_ 20
#define EPSF_ 1e-5f

typedef float f32x4 __attribute__((ext_vector_type(4)));

__device__ float g_coef[8];   // [0..3] = h_pre[s], [4..7] = c[s]

__global__ void hyperconn_coeff(const float* __restrict__ hpre_l,
                                const float* __restrict__ hpost_l,
                                const float* __restrict__ hres)
{
    if (threadIdx.x != 0) return;

    float M[S_][S_];
    #pragma unroll
    for (int i = 0; i < S_; ++i)
        #pragma unroll
        for (int j = 0; j < S_; ++j)
            M[i][j] = __expf(hres[i * S_ + j]);

    for (int it = 0; it < NITER_; ++it) {
        #pragma unroll
        for (int i = 0; i < S_; ++i) {
            float inv = 1.0f / (M[i][0] + M[i][1] + M[i][2] + M[i][3] + EPSF_);
            M[i][0] *= inv; M[i][1] *= inv; M[i][2] *= inv; M[i][3] *= inv;
        }
        #pragma unroll
        for (int j = 0; j < S_; ++j) {
            float inv = 1.0f / (M[0][j] + M[1][j] + M[2][j] + M[3][j] + EPSF_);
            M[0][j] *= inv; M[1][j] *= inv; M[2][j] *= inv; M[3][j] *= inv;
        }
    }

    #pragma unroll
    for (int s = 0; s < S_; ++s) {
        g_coef[s] = 1.0f / (1.0f + __expf(-hpre_l[s]));    // h_pre[s]
        float c = 0.0f;
        #pragma unroll
        for (int r = 0; r < S_; ++r)
            c += M[s][r] * (2.0f / (1.0f + __expf(-hpost_l[r])));
        g_coef[S_ + s] = c;                                 // c[s]
    }
}

__global__ __launch_bounds__(256, 4) void hyperconn_main(
    const float* __restrict__ res,
    const float* __restrict__ w,
    float* __restrict__ out,
    const int n_rows)
{
    const int lane = threadIdx.x & 63;
    const int gw   = (int)((blockIdx.x * blockDim.x + threadIdx.x) >> 6);
    const int nw   = (int)((gridDim.x * blockDim.x) >> 6);

    // ---- coefficients: 8 uniform floats (SGPR via uniform load) ----
    const float h0 = g_coef[0], h1 = g_coef[1], h2 = g_coef[2], h3 = g_coef[3];
    const float cs0 = g_coef[4], cs1 = g_coef[5], cs2 = g_coef[6], cs3 = g_coef[7];
    const float cs[S_] = {cs0, cs1, cs2, cs3};

    const f32x4* res4 = reinterpret_cast<const f32x4*>(res);
    const f32x4* w4   = reinterpret_cast<const f32x4*>(w);
    f32x4*       out4 = reinterpret_cast<f32x4*>(out);

    const size_t sstride = (size_t)T_ * (D_ / 4);   // f32x4s between streams

    // ---- weight: 16 floats per lane, hoisted out of the row loop ----
    f32x4 wt[4];
    #pragma unroll
    for (int k = 0; k < 4; ++k)
        wt[k] = w4[(k << 6) + lane];

    for (int n = gw; n < n_rows; n += nw) {
        const int b = n >> 12;            // T = 4096
        const int t = n & (T_ - 1);
        const size_t rb = ((size_t)(b * S_) * T_ + t) * (D_ / 4) + lane;

        // ---- load 4 streams x 4 chunks (16 x 16B in flight per lane) ----
        f32x4 r[S_][4];
        #pragma unroll
        for (int s = 0; s < S_; ++s)
            #pragma unroll
            for (int k = 0; k < 4; ++k)
                r[s][k] = res4[rb + (size_t)s * sstride + (k << 6)];

        // ---- aggregate with h_pre ----
        f32x4 agg[4];
        #pragma unroll
        for (int k = 0; k < 4; ++k)
            agg[k] = h0 * r[0][k] + h1 * r[1][k] + h2 * r[2][k] + h3 * r[3][k];

        // ---- sum of squares: 16 per-lane values + 6-step butterfly ----
        float ssq = 0.0f;
        #pragma unroll
        for (int k = 0; k < 4; ++k)
            ssq += agg[k].x*agg[k].x + agg[k].y*agg[k].y
                 + agg[k].z*agg[k].z + agg[k].w*agg[k].w;
        #pragma unroll
        for (int off = 1; off <= 32; off <<= 1)
            ssq += __shfl_xor(ssq, off, 64);

        const float inv_rms = rsqrtf(ssq * (1.0f / (float)D_) + EPSF_);

        // ---- normalize, scale by weight, distribute, add residual ----
        #pragma unroll
        for (int k = 0; k < 4; ++k) {
            const f32x4 nrm = agg[k] * inv_rms * wt[k];
            #pragma unroll
            for (int s = 0; s < S_; ++s)
                out4[rb + (size_t)s * sstride + (k << 6)] = r[s][k] + nrm * cs[s];
        }
    }
}

extern "C" void kernel_launch(void* const* d_in, const int* in_sizes, int n_in,
                              void* d_out, int out_size, void* d_ws, size_t ws_size,
                              hipStream_t stream) {
    const float* res     = (const float*)d_in[0];   // (B*S, T, D) f32
    const float* weight  = (const float*)d_in[1];   // (D,) f32
    const float* hpre_l  = (const float*)d_in[2];   // (S,) f32
    const float* hpost_l = (const float*)d_in[3];   // (S,) f32
    const float* hres    = (const float*)d_in[4];   // (S,S) f32
    float*       out     = (float*)d_out;

    hyperconn_coeff<<<1, 64, 0, stream>>>(hpre_l, hpost_l, hres);

    // persistent: 1024 blocks x 4 waves = 4096 waves, 4 rows each
    const int n_rows = in_sizes[0] / (S_ * D_);     // 16384 for B=4,T=4096
    hyperconn_main<<<1024, 256, 0, stream>>>(res, weight, out, n_rows);
}